// Round 16
// baseline (352.298 us; speedup 1.0000x reference)
//
#include <hip/hip_runtime.h>
#include <cstdint>
#include <cstddef>

// GRU B=16384 T=64 H=32, 3 bidir layers + FC(64->2) + tanh.
// R15: 2-wave gate-half split. A pair of waves shares 16 seqs; wave T takes
// gate tiles {r_T, z_T, n_T} (units 8a+4T+b under the row permutation):
// per-wave MFMA 18->9, gate updates 8->4, waves double to 4096 (4/SIMD) with
// per-SIMD work unchanged. h-exchange is lane-aligned: own 8B ds_write_b64 +
// partner 8B ds_read_b64 + one __syncthreads (parity double-buffered).
// Datapath from R14: f16 weights/h/activations, fp32 acc, (T,B,64) layout,
// exp2-folded weights, shared rcp, delayed h-stores (wave0), FC fused in L2.

#define BB 16384
#define TT 64
#define ST ((size_t)BB * 64)        // shorts per t-plane
#define PT ((size_t)TT * BB * 2)    // floats per direction-partial buffer

typedef __attribute__((ext_vector_type(8))) _Float16 f16x8;
typedef __attribute__((ext_vector_type(4))) float f32x4;

#if __has_builtin(__builtin_amdgcn_exp2f)
#define EXP2(x) __builtin_amdgcn_exp2f(x)
#else
#define EXP2(x) exp2f(x)
#endif
#if __has_builtin(__builtin_amdgcn_rcpf)
#define RCP(x) __builtin_amdgcn_rcpf(x)
#else
#define RCP(x) (1.0f / (x))
#endif

#define SR (-1.4426950408889634f)   // -log2(e)   for r,z gates
#define SN (-2.8853900817779268f)   // -2*log2(e) for n gate

__device__ __forceinline__ float tanh_fast(float x) { return 2.0f / (1.0f + __expf(-2.0f * x)) - 1.0f; }
__device__ __forceinline__ unsigned short f2h(float f) {
    _Float16 h = (_Float16)f;                      // RNE
    return __builtin_bit_cast(unsigned short, h);
}
__device__ __forceinline__ unsigned int cvt_pkh(float a, float b) {
#if __has_builtin(__builtin_amdgcn_cvt_pkrtz)
    typedef __fp16 h2_t __attribute__((ext_vector_type(2)));
    h2_t p = __builtin_amdgcn_cvt_pkrtz(a, b);
    return __builtin_bit_cast(unsigned int, p);
#else
    return (unsigned int)f2h(a) | ((unsigned int)f2h(b) << 16);
#endif
}
__device__ __forceinline__ f32x4 mfma16h(f16x8 a, f16x8 b, f32x4 c) {
    return __builtin_amdgcn_mfma_f32_16x16x32_f16(a, b, c, 0, 0, 0);
}

// Gates for a q-pair. Inputs are exp2-prescaled preactivations (C carried bias).
__device__ __forceinline__ void gate_pair(float aR0, float aR1, float aZ0, float aZ1,
                                          float xN0, float xN1, float hN0, float hN1,
                                          float& hp0, float& hp1) {
    float er0 = EXP2(aR0), er1 = EXP2(aR1);
    float ez0 = EXP2(aZ0), ez1 = EXP2(aZ1);
    float Ar0 = 1.f + er0, Ar1 = 1.f + er1;
    float Az0 = 1.f + ez0, Az1 = 1.f + ez1;
    float iR = RCP(Ar0 * Ar1);
    float iZ = RCP(Az0 * Az1);
    float r0 = iR * Ar1, r1 = iR * Ar0;
    float z0 = iZ * Az1, z1 = iZ * Az0;
    float v0 = fmaf(r0, hN0, xN0), v1 = fmaf(r1, hN1, xN1);
    float en0 = EXP2(v0), en1 = EXP2(v1);
    float An0 = 1.f + en0, An1 = 1.f + en1;
    float iN = RCP(An0 * An1);
    float n0 = fmaf(2.f, iN * An1, -1.f);
    float n1 = fmaf(2.f, iN * An0, -1.f);
    hp0 = fmaf(z0, hp0 - n0, n0);
    hp1 = fmaf(z1, hp1 - n1, n1);
}

// A: lane = A[m=lane&15][k=(lane>>4)*8+j]   B: lane = B[k=(lane>>4)*8+j][n=lane&15]
// D: lane = D[row=(lane>>4)*4+reg][col=lane&15]
// Row permutation within each 32-row gate block: position 8qd+4T+q holds that unit.
// Wave T owns tiles {block i, half T} for i=0(r),1(z),2(n): units 8a+4T+b.

template<bool IS_L0, bool IS_LAST>
__global__ __launch_bounds__(256, 2)
void gru_mfma(const float* __restrict__ x0,
              const unsigned short* __restrict__ bin,      // f16 bits (T,B,64)
              const float* __restrict__ Wih,               // (2,96,I)
              const float* __restrict__ Whh,               // (2,96,32)
              const float* __restrict__ bih,               // (2,96)
              const float* __restrict__ bhh,               // (2,96)
              unsigned short* __restrict__ bout,           // f16 bits (T,B,64)
              const float* __restrict__ Wfc,               // (2,64)  [LAST]
              float* __restrict__ pbase)                   // (2,T,B,2) fp32 [LAST]
{
    __shared__ uint2 hx[2][2][2][64];   // [stepParity][pair][T][lane]
    __shared__ float2 fcx[2][2][16];    // [pair][T][col]

    const int tid  = threadIdx.x;
    const int lane = tid & 63;
    const int wv   = tid >> 6;
    const int pr   = wv >> 1;                    // pair in block
    const int Tw   = wv & 1;                     // gate-half of this wave
    const int g2   = blockIdx.x * 2 + pr;        // 0..2047
    const int d    = g2 >> 10;
    const int b0   = (g2 & 1023) * 16;           // 16 seqs per pair
    const int col  = lane & 15;
    const int qd   = lane >> 4;

    // ---- Whh A-frags (3 tiles), permuted rows, exp2-prescaled ----
    f16x8 whhF[3];
    {
        const float* wsrc = Whh + d * 96 * 32;
        #pragma unroll
        for (int i = 0; i < 3; ++i) {
            const float sc = (i < 2) ? SR : SN;
            const int row = i * 32 + 8 * (col >> 2) + 4 * Tw + (col & 3);
            const float* pr2 = wsrc + row * 32 + qd * 8;
            unsigned short wbits[8];
            #pragma unroll
            for (int j = 0; j < 8; ++j) wbits[j] = f2h(pr2[j] * sc);
            whhF[i] = __builtin_bit_cast(f16x8, *(uint4*)wbits);
        }
    }

    // ---- Wih A-frags (3 tiles) or L0 scalar weights ----
    f16x8 wihF[3][2];
    float w0c[3][4], w1c[3][4];
    if constexpr (!IS_L0) {
        const float* wsrc = Wih + d * 96 * 64;
        #pragma unroll
        for (int i = 0; i < 3; ++i) {
            const float sc = (i < 2) ? SR : SN;
            const int row = i * 32 + 8 * (col >> 2) + 4 * Tw + (col & 3);
            #pragma unroll
            for (int kc = 0; kc < 2; ++kc) {
                const float* pr2 = wsrc + row * 64 + kc * 32 + qd * 8;
                unsigned short wbits[8];
                #pragma unroll
                for (int j = 0; j < 8; ++j) wbits[j] = f2h(pr2[j] * sc);
                wihF[i][kc] = __builtin_bit_cast(f16x8, *(uint4*)wbits);
            }
        }
    } else {
        #pragma unroll
        for (int i = 0; i < 3; ++i) {
            const float sc = (i < 2) ? SR : SN;
            #pragma unroll
            for (int q = 0; q < 4; ++q) {
                const int row = i * 32 + 8 * qd + 4 * Tw + q;
                const float* pr2 = Wih + d * 96 * 2 + row * 2;
                w0c[i][q] = pr2[0] * sc;
                w1c[i][q] = pr2[1] * sc;
            }
        }
    }

    // ---- biases as C-operand frags ----
    f32x4 biasIn[3], biasHN;
    {
        const float* bi = bih + d * 96;
        const float* bh = bhh + d * 96;
        #pragma unroll
        for (int i = 0; i < 2; ++i) {
            const int off = i * 32 + 8 * qd + 4 * Tw;
            float4 a = *(const float4*)(bi + off);
            float4 b = *(const float4*)(bh + off);
            biasIn[i][0] = (a.x + b.x) * SR; biasIn[i][1] = (a.y + b.y) * SR;
            biasIn[i][2] = (a.z + b.z) * SR; biasIn[i][3] = (a.w + b.w) * SR;
        }
        const int off = 64 + 8 * qd + 4 * Tw;
        float4 a = *(const float4*)(bi + off);
        float4 b = *(const float4*)(bh + off);
        biasIn[2][0] = a.x * SN; biasIn[2][1] = a.y * SN;
        biasIn[2][2] = a.z * SN; biasIn[2][3] = a.w * SN;
        biasHN[0] = b.x * SN; biasHN[1] = b.y * SN;
        biasHN[2] = b.z * SN; biasHN[3] = b.w * SN;
    }

    // ---- FC weights per lane (LAST): unit u = 8*qd + 4*Tw + q ----
    float wf0[4], wf1[4];
    if constexpr (IS_LAST) {
        #pragma unroll
        for (int q = 0; q < 4; ++q) {
            const int u = 8 * qd + 4 * Tw + q;
            wf0[q] = Wfc[d * 32 + u];
            wf1[q] = Wfc[64 + d * 32 + u];
        }
    }

    const int t0 = d ? (TT - 1) : 0;
    const int dt = d ? -1 : 1;
    const ptrdiff_t dplane = (ptrdiff_t)dt * (ptrdiff_t)ST;

    f16x8 hF = {};
    float hprev[4] = {0.f, 0.f, 0.f, 0.f};

    // LDS exchange slots (per stream parity)
    uint2* hxwA = &hx[0][pr][Tw][lane];
    const uint2* hxrA = &hx[0][pr][Tw ^ 1][lane];
    uint2* hxwB = &hx[1][pr][Tw][lane];
    const uint2* hxrB = &hx[1][pr][Tw ^ 1][lane];
    float2* fcw = &fcx[pr][Tw][0];
    const float2* fcr = &fcx[pr][Tw ^ 1][0];

    auto REC = [&](f32x4 (&acc)[3], f32x4& accHN) {
        acc[0] = mfma16h(whhF[0], hF, acc[0]);
        acc[1] = mfma16h(whhF[1], hF, acc[1]);
        accHN  = mfma16h(whhF[2], hF, biasHN);
    };

    auto PROJ = [&](f32x4 (&accN)[3], uint4 nx0, uint4 nx1, float2 nxs) {
        if constexpr (!IS_L0) {
            f16x8 a0 = __builtin_bit_cast(f16x8, nx0);
            f16x8 a1 = __builtin_bit_cast(f16x8, nx1);
            #pragma unroll
            for (int i = 0; i < 3; ++i) {
                accN[i] = mfma16h(wihF[i][0], a0, biasIn[i]);
                accN[i] = mfma16h(wihF[i][1], a1, accN[i]);
            }
        } else {
            #pragma unroll
            for (int i = 0; i < 3; ++i)
                #pragma unroll
                for (int q = 0; q < 4; ++q)
                    accN[i][q] = fmaf(nxs.x, w0c[i][q], fmaf(nxs.y, w1c[i][q], biasIn[i][q]));
        }
    };

    // gates (4 updates) + lane-aligned cross-wave exchange + store
    auto GATES = [&](f32x4 (&acc)[3], f32x4& accHN, unsigned short* outp,
                     uint2* hxw, const uint2* hxr,
                     uint4& hwP, unsigned short*& opP, float* poutp) {
        float h0 = hprev[0], h1 = hprev[1], h2 = hprev[2], h3 = hprev[3];
        gate_pair(acc[0][0], acc[0][1], acc[1][0], acc[1][1],
                  acc[2][0], acc[2][1], accHN[0], accHN[1], h0, h1);
        gate_pair(acc[0][2], acc[0][3], acc[1][2], acc[1][3],
                  acc[2][2], acc[2][3], accHN[2], accHN[3], h2, h3);
        hprev[0] = h0; hprev[1] = h1; hprev[2] = h2; hprev[3] = h3;
        uint2 own = make_uint2(cvt_pkh(h0, h1), cvt_pkh(h2, h3));
        *hxw = own;
        float p0 = 0.f, p1 = 0.f;
        if constexpr (IS_LAST) {
            #pragma unroll
            for (int q = 0; q < 4; ++q) {
                p0 = fmaf(hprev[q], wf0[q], p0);
                p1 = fmaf(hprev[q], wf1[q], p1);
            }
            p0 += __shfl_xor(p0, 16); p0 += __shfl_xor(p0, 32);
            p1 += __shfl_xor(p1, 16); p1 += __shfl_xor(p1, 32);
            if (qd == 0) fcw[col] = make_float2(p0, p1);
        }
        __syncthreads();
        uint2 oth = *hxr;
        uint4 comb = (Tw == 0) ? make_uint4(own.x, own.y, oth.x, oth.y)
                               : make_uint4(oth.x, oth.y, own.x, own.y);
        hF = __builtin_bit_cast(f16x8, comb);
        if constexpr (IS_LAST) {
            if (Tw == 0 && qd == 0) {
                float2 o2 = fcr[col];
                *(float2*)poutp = make_float2(p0 + o2.x, p1 + o2.y);
            }
        } else {
            if (Tw == 0) {                      // delayed 16B store of combined h
                *(uint4*)opP = hwP;
                hwP = comb;
                opP = outp;
            }
        }
    };

    // ---- x streams: even loads x[2k+2], odd loads x[2k+3] ----
    f32x4 accA[3], accB[3], accHN;
    uint4 xc0 = {}, xc1 = {}, xe0 = {}, xe1 = {};
    float2 xsc = {}, xse = {};
    const unsigned short* xptrE = nullptr; const unsigned short* xptrO = nullptr;
    const float* xfpE = nullptr; const float* xfpO = nullptr;

    if constexpr (!IS_L0) {
        const unsigned short* p0 = bin + (size_t)t0 * ST + (size_t)(b0 + col) * 64 + qd * 8;
        uint4 a = *(const uint4*)p0, b = *(const uint4*)(p0 + 32);
        PROJ(accA, a, b, {});
        const unsigned short* p1 = p0 + dplane;
        xc0 = *(const uint4*)p1; xc1 = *(const uint4*)(p1 + 32);
        xptrE = p0 + 2 * dplane;
        xptrO = p0 + 3 * dplane;
    } else {
        const float* p0 = x0 + ((size_t)(b0 + col) * TT + t0) * 2;
        float2 xs0 = *(const float2*)p0;
        PROJ(accA, {}, {}, xs0);
        xsc = *(const float2*)(p0 + dt * 2);
        xfpE = p0 + dt * 4;
        xfpO = p0 + dt * 6;
    }

    unsigned short* optrA = nullptr; unsigned short* optrB = nullptr;
    float* poutA = nullptr; float* poutB = nullptr;
    const ptrdiff_t dpp = (ptrdiff_t)dt * (ptrdiff_t)BB * 2;
    if constexpr (IS_LAST) {
        poutA = pbase + (size_t)d * PT + ((size_t)t0 * BB + b0 + col) * 2;
        poutB = poutA + dpp;
    } else {
        optrA = bout + (size_t)t0 * ST + (size_t)(b0 + col) * 64 + d * 32 + qd * 8;
        optrB = optrA + dplane;
    }

    uint4 hwPrevA = {}, hwPrevB = {};
    unsigned short* opPrevA = optrA;
    unsigned short* opPrevB = optrB;

    for (int k = 0; k < 31; ++k) {                    // steps 0..61
        if constexpr (!IS_L0) {
            xe0 = *(const uint4*)xptrE; xe1 = *(const uint4*)(xptrE + 32);
            xptrE += 2 * dplane;
        } else { xse = *(const float2*)xfpE; xfpE += dt * 4; }
        REC(accA, accHN);
        PROJ(accB, xc0, xc1, xsc);
        GATES(accA, accHN, optrA, hxwA, hxrA, hwPrevA, opPrevA, poutA);
        if constexpr (IS_LAST) poutA += 2 * dpp; else optrA += 2 * dplane;
        if constexpr (!IS_L0) {
            xc0 = *(const uint4*)xptrO; xc1 = *(const uint4*)(xptrO + 32);
            xptrO += 2 * dplane;
        } else { xsc = *(const float2*)xfpO; xfpO += dt * 4; }
        REC(accB, accHN);
        PROJ(accA, xe0, xe1, xse);
        GATES(accB, accHN, optrB, hxwB, hxrB, hwPrevB, opPrevB, poutB);
        if constexpr (IS_LAST) poutB += 2 * dpp; else optrB += 2 * dplane;
    }
    REC(accA, accHN);                                 // step 62
    PROJ(accB, xc0, xc1, xsc);
    GATES(accA, accHN, optrA, hxwA, hxrA, hwPrevA, opPrevA, poutA);
    REC(accB, accHN);                                 // step 63
    GATES(accB, accHN, optrB, hxwB, hxrB, hwPrevB, opPrevB, poutB);
    if constexpr (!IS_LAST) {
        if (Tw == 0) {
            *(uint4*)opPrevA = hwPrevA;               // flush banked values
            *(uint4*)opPrevB = hwPrevB;
        }
    }
}

// out[b][t] = tanh(pf[t][b] + pb[t][b] + bfc), with an LDS 64x64 transpose
__global__ __launch_bounds__(256)
void fc_finish(const float* __restrict__ pf,    // (T,B,2)
               const float* __restrict__ pb,    // (T,B,2)
               const float* __restrict__ bfc,   // (2,)
               float* __restrict__ out)         // (B,T,2)
{
    __shared__ float2 tile[64][65];
    const int tid = threadIdx.x;
    const int bbase = blockIdx.x * 64;
    const float c0 = bfc[0], c1 = bfc[1];
    #pragma unroll
    for (int tp = 0; tp < 16; ++tp) {             // read coalesced over b
        const int t = tp * 4 + (tid >> 6);
        const int bl = tid & 63;
        const size_t idx = ((size_t)t * BB + bbase + bl) * 2;
        float2 vf = *(const float2*)(pf + idx);
        float2 vb = *(const float2*)(pb + idx);
        float2 o;
        o.x = tanh_fast(vf.x + vb.x + c0);
        o.y = tanh_fast(vf.y + vb.y + c1);
        tile[t][bl] = o;
    }
    __syncthreads();
    #pragma unroll
    for (int bp = 0; bp < 16; ++bp) {             // write coalesced over t
        const int bl = bp * 4 + (tid >> 6);
        const int t = tid & 63;
        *(float2*)(out + ((size_t)(bbase + bl) * TT + t) * 2) = tile[t][bl];
    }
}

extern "C" void kernel_launch(void* const* d_in, const int* in_sizes, int n_in,
                              void* d_out, int out_size, void* d_ws, size_t ws_size,
                              hipStream_t stream)
{
    const float* x    = (const float*)d_in[0];
    const float* Wih0 = (const float*)d_in[1];
    const float* Whh0 = (const float*)d_in[2];
    const float* bih0 = (const float*)d_in[3];
    const float* bhh0 = (const float*)d_in[4];
    const float* WihL = (const float*)d_in[5];
    const float* WhhL = (const float*)d_in[6];
    const float* bihL = (const float*)d_in[7];
    const float* bhhL = (const float*)d_in[8];
    const float* Wfc  = (const float*)d_in[9];
    const float* bfc  = (const float*)d_in[10];

    unsigned short* buf0 = (unsigned short*)d_ws;           // (T,B,64) f16
    unsigned short* buf1 = buf0 + (size_t)TT * BB * 64;     // (T,B,64) f16
    float* pbase = (float*)d_ws;                            // (2,T,B,2) fp32, reuses buf0
    float* out = (float*)d_out;

    gru_mfma<true, false><<<1024, 256, 0, stream>>>(
        x, nullptr, Wih0, Whh0, bih0, bhh0, buf0, nullptr, nullptr);
    gru_mfma<false, false><<<1024, 256, 0, stream>>>(
        nullptr, buf0, WihL, WhhL, bihL, bhhL, buf1, nullptr, nullptr);
    gru_mfma<false, true><<<1024, 256, 0, stream>>>(
        nullptr, buf1, WihL + 2 * 96 * 64, WhhL + 2 * 96 * 32,
        bihL + 2 * 96, bhhL + 2 * 96, nullptr, Wfc, pbase);
    fc_finish<<<BB / 64, 256, 0, stream>>>(
        pbase, pbase + PT, bfc, out);
}

// Round 17
// 269.589 us; speedup vs baseline: 1.3068x; 1.3068x over previous
//
#include <hip/hip_runtime.h>
#include <cstdint>
#include <cstddef>

// GRU B=16384 T=64 H=32, 3 bidir layers + FC(64->2) + tanh.
// R16: direction-split activation buffers (2,T,B,32) f16. In the old (T,B,64)
// layout every 128B line was half-written by a fwd wave (units 0-31 at s=t)
// and half by a bwd wave (units 32-63 at s=63-t) -> every store RFO-fetched
// the line from HBM (~128 MB/dispatch, the FETCH_SIZE seen even on L0 whose
// real input is 8 MB). Split buffers make each wave's store 1KB of full
// lines -> RFO gone. Reader: k=0..31 frag from fwd buf, k=32..63 from bwd.
// Rest identical to R14: f16 datapath, fp32 acc, 16 seqs/wave, permuted gate
// rows, zero-LDS recurrence, exp2-folded weights, shared rcp, delayed
// h-stores, FC fused into L2 + fc_finish transpose.

#define BB 16384
#define TT 64
#define PS ((size_t)BB * 32)        // shorts per t-plane per direction
#define DS ((size_t)TT * PS)        // shorts per direction buffer
#define PT ((size_t)TT * BB * 2)    // floats per direction-partial buffer

typedef __attribute__((ext_vector_type(8))) _Float16 f16x8;
typedef __attribute__((ext_vector_type(4))) float f32x4;

#if __has_builtin(__builtin_amdgcn_exp2f)
#define EXP2(x) __builtin_amdgcn_exp2f(x)
#else
#define EXP2(x) exp2f(x)
#endif
#if __has_builtin(__builtin_amdgcn_rcpf)
#define RCP(x) __builtin_amdgcn_rcpf(x)
#else
#define RCP(x) (1.0f / (x))
#endif

#define SR (-1.4426950408889634f)   // -log2(e)   for r,z gates
#define SN (-2.8853900817779268f)   // -2*log2(e) for n gate

__device__ __forceinline__ float tanh_fast(float x) { return 2.0f / (1.0f + __expf(-2.0f * x)) - 1.0f; }
__device__ __forceinline__ unsigned short f2h(float f) {
    _Float16 h = (_Float16)f;                      // RNE
    return __builtin_bit_cast(unsigned short, h);
}
__device__ __forceinline__ unsigned int cvt_pkh(float a, float b) {
#if __has_builtin(__builtin_amdgcn_cvt_pkrtz)
    typedef __fp16 h2_t __attribute__((ext_vector_type(2)));
    h2_t p = __builtin_amdgcn_cvt_pkrtz(a, b);
    return __builtin_bit_cast(unsigned int, p);
#else
    return (unsigned int)f2h(a) | ((unsigned int)f2h(b) << 16);
#endif
}
__device__ __forceinline__ f32x4 mfma16h(f16x8 a, f16x8 b, f32x4 c) {
    return __builtin_amdgcn_mfma_f32_16x16x32_f16(a, b, c, 0, 0, 0);
}

// Gates for a q-pair. Inputs are exp2-prescaled preactivations (C carried bias).
__device__ __forceinline__ void gate_pair(float aR0, float aR1, float aZ0, float aZ1,
                                          float xN0, float xN1, float hN0, float hN1,
                                          float& hp0, float& hp1) {
    float er0 = EXP2(aR0), er1 = EXP2(aR1);
    float ez0 = EXP2(aZ0), ez1 = EXP2(aZ1);
    float Ar0 = 1.f + er0, Ar1 = 1.f + er1;
    float Az0 = 1.f + ez0, Az1 = 1.f + ez1;
    float iR = RCP(Ar0 * Ar1);
    float iZ = RCP(Az0 * Az1);
    float r0 = iR * Ar1, r1 = iR * Ar0;
    float z0 = iZ * Az1, z1 = iZ * Az0;
    float v0 = fmaf(r0, hN0, xN0), v1 = fmaf(r1, hN1, xN1);
    float en0 = EXP2(v0), en1 = EXP2(v1);
    float An0 = 1.f + en0, An1 = 1.f + en1;
    float iN = RCP(An0 * An1);
    float n0 = fmaf(2.f, iN * An1, -1.f);
    float n1 = fmaf(2.f, iN * An0, -1.f);
    hp0 = fmaf(z0, hp0 - n0, n0);
    hp1 = fmaf(z1, hp1 - n1, n1);
}

// A: lane = A[m=lane&15][k=(lane>>4)*8+j]   B: lane = B[k=(lane>>4)*8+j][n=lane&15]
// D: lane = D[row=(lane>>4)*4+reg][col=lane&15]
// Gate-row permutation: block row position (T*16 + qd*4 + q) <- original unit 8qd+4T+q.

template<bool IS_L0, bool IS_LAST>
__global__ __launch_bounds__(256, 2)
void gru_mfma(const float* __restrict__ x0,
              const unsigned short* __restrict__ bin,      // f16 bits (2,T,B,32)
              const float* __restrict__ Wih,               // (2,96,I)
              const float* __restrict__ Whh,               // (2,96,32)
              const float* __restrict__ bih,               // (2,96)
              const float* __restrict__ bhh,               // (2,96)
              unsigned short* __restrict__ bout,           // f16 bits (2,T,B,32)
              const float* __restrict__ Wfc,               // (2,64)  [LAST]
              float* __restrict__ pbase)                   // (2,T,B,2) fp32 [LAST]
{
    const int tid  = threadIdx.x;
    const int lane = tid & 63;
    const int wv   = tid >> 6;
    const int g    = blockIdx.x * 4 + wv;        // 0..2047
    const int d    = g >> 10;
    const int b0   = (g & 1023) * 16;            // 16 seqs per wave
    const int col  = lane & 15;
    const int qd   = lane >> 4;

    // ---- Whh A-frags (single f16), permuted rows, exp2-prescaled ----
    f16x8 whhF[6];
    {
        const float* wsrc = Whh + d * 96 * 32;
        #pragma unroll
        for (int t = 0; t < 6; ++t) {
            const float sc = (t < 4) ? SR : SN;
            const int row = (t >> 1) * 32 + 8 * (col >> 2) + 4 * (t & 1) + (col & 3);
            const float* pr = wsrc + row * 32 + qd * 8;
            unsigned short wbits[8];
            #pragma unroll
            for (int j = 0; j < 8; ++j) wbits[j] = f2h(pr[j] * sc);
            whhF[t] = __builtin_bit_cast(f16x8, *(uint4*)wbits);
        }
    }

    // ---- Wih A-frags (single f16, permuted, prescaled) or L0 scalar weights ----
    f16x8 wihF[6][2];
    float w0c[6][4], w1c[6][4];
    if constexpr (!IS_L0) {
        const float* wsrc = Wih + d * 96 * 64;
        #pragma unroll
        for (int t = 0; t < 6; ++t) {
            const float sc = (t < 4) ? SR : SN;
            const int row = (t >> 1) * 32 + 8 * (col >> 2) + 4 * (t & 1) + (col & 3);
            #pragma unroll
            for (int kc = 0; kc < 2; ++kc) {
                const float* pr = wsrc + row * 64 + kc * 32 + qd * 8;
                unsigned short wbits[8];
                #pragma unroll
                for (int j = 0; j < 8; ++j) wbits[j] = f2h(pr[j] * sc);
                wihF[t][kc] = __builtin_bit_cast(f16x8, *(uint4*)wbits);
            }
        }
    } else {
        #pragma unroll
        for (int t = 0; t < 6; ++t) {
            const float sc = (t < 4) ? SR : SN;
            #pragma unroll
            for (int q = 0; q < 4; ++q) {
                const int row = (t >> 1) * 32 + 8 * qd + 4 * (t & 1) + q;
                const float* pr = Wih + d * 96 * 2 + row * 2;
                w0c[t][q] = pr[0] * sc;
                w1c[t][q] = pr[1] * sc;
            }
        }
    }

    // ---- biases as C-operand frags (prescaled) ----
    f32x4 biasIn[6], biasHN[2];
    {
        const float* bi = bih + d * 96;
        const float* bh = bhh + d * 96;
        #pragma unroll
        for (int t = 0; t < 4; ++t) {
            const int off = (t >> 1) * 32 + 8 * qd + 4 * (t & 1);
            float4 a = *(const float4*)(bi + off);
            float4 b = *(const float4*)(bh + off);
            biasIn[t][0] = (a.x + b.x) * SR; biasIn[t][1] = (a.y + b.y) * SR;
            biasIn[t][2] = (a.z + b.z) * SR; biasIn[t][3] = (a.w + b.w) * SR;
        }
        #pragma unroll
        for (int T = 0; T < 2; ++T) {
            const int off = 64 + 8 * qd + 4 * T;
            float4 a = *(const float4*)(bi + off);
            float4 b = *(const float4*)(bh + off);
            biasIn[4 + T][0] = a.x * SN; biasIn[4 + T][1] = a.y * SN;
            biasIn[4 + T][2] = a.z * SN; biasIn[4 + T][3] = a.w * SN;
            biasHN[T][0] = b.x * SN; biasHN[T][1] = b.y * SN;
            biasHN[T][2] = b.z * SN; biasHN[T][3] = b.w * SN;
        }
    }

    // ---- FC weights per lane (LAST): unit u = 8*qd + 4*T + q ----
    float wf0[2][4], wf1[2][4];
    if constexpr (IS_LAST) {
        #pragma unroll
        for (int T = 0; T < 2; ++T)
            #pragma unroll
            for (int q = 0; q < 4; ++q) {
                const int u = 8 * qd + 4 * T + q;
                wf0[T][q] = Wfc[d * 32 + u];
                wf1[T][q] = Wfc[64 + d * 32 + u];
            }
    }

    const int t0 = d ? (TT - 1) : 0;
    const int dt = d ? -1 : 1;
    const ptrdiff_t dplane = (ptrdiff_t)dt * (ptrdiff_t)PS;   // one t-plane step

    f16x8 hF = {};
    float hprev[2][4] = {{0.f,0.f,0.f,0.f},{0.f,0.f,0.f,0.f}};

    auto REC = [&](f32x4 (&acc)[6], f32x4 (&accHN)[2]) {
        #pragma unroll
        for (int t = 0; t < 4; ++t)
            acc[t] = mfma16h(whhF[t], hF, acc[t]);
        #pragma unroll
        for (int T = 0; T < 2; ++T)
            accHN[T] = mfma16h(whhF[4 + T], hF, biasHN[T]);
    };

    auto PROJ = [&](f32x4 (&accN)[6], uint4 nx0, uint4 nx1, float2 nxs) {
        if constexpr (!IS_L0) {
            f16x8 a0 = __builtin_bit_cast(f16x8, nx0);   // k 0..31  = fwd units
            f16x8 a1 = __builtin_bit_cast(f16x8, nx1);   // k 32..63 = bwd units
            #pragma unroll
            for (int t = 0; t < 6; ++t) {
                accN[t] = mfma16h(wihF[t][0], a0, biasIn[t]);
                accN[t] = mfma16h(wihF[t][1], a1, accN[t]);
            }
        } else {
            #pragma unroll
            for (int t = 0; t < 6; ++t)
                #pragma unroll
                for (int q = 0; q < 4; ++q)
                    accN[t][q] = fmaf(nxs.x, w0c[t][q], fmaf(nxs.y, w1c[t][q], biasIn[t][q]));
        }
    };

    // ---- gates; then either delayed h-store (L0/L1) or FC partial (LAST) ----
    auto GATES = [&](f32x4 (&acc)[6], f32x4 (&accHN)[2], unsigned short* outp,
                     uint4& hwP, unsigned short*& opP, float* poutp) {
        unsigned int hw[4];
        #pragma unroll
        for (int T = 0; T < 2; ++T) {
            float h0 = hprev[T][0], h1 = hprev[T][1];
            float h2 = hprev[T][2], h3 = hprev[T][3];
            gate_pair(acc[T][0], acc[T][1], acc[2 + T][0], acc[2 + T][1],
                      acc[4 + T][0], acc[4 + T][1], accHN[T][0], accHN[T][1], h0, h1);
            gate_pair(acc[T][2], acc[T][3], acc[2 + T][2], acc[2 + T][3],
                      acc[4 + T][2], acc[4 + T][3], accHN[T][2], accHN[T][3], h2, h3);
            hprev[T][0] = h0; hprev[T][1] = h1; hprev[T][2] = h2; hprev[T][3] = h3;
            hw[2 * T]     = cvt_pkh(h0, h1);
            hw[2 * T + 1] = cvt_pkh(h2, h3);
        }
        hF = __builtin_bit_cast(f16x8, *(uint4*)hw);
        if constexpr (IS_LAST) {
            float p0 = 0.f, p1 = 0.f;
            #pragma unroll
            for (int T = 0; T < 2; ++T)
                #pragma unroll
                for (int q = 0; q < 4; ++q) {
                    p0 = fmaf(hprev[T][q], wf0[T][q], p0);
                    p1 = fmaf(hprev[T][q], wf1[T][q], p1);
                }
            p0 += __shfl_xor(p0, 16); p0 += __shfl_xor(p0, 32);
            p1 += __shfl_xor(p1, 16); p1 += __shfl_xor(p1, 32);
            if (qd == 0) *(float2*)poutp = make_float2(p0, p1);
        } else {
            *(uint4*)opP = hwP;                 // store the 2-steps-old value
            hwP = *(uint4*)hw;                  // bank this step's value
            opP = outp;
        }
    };

    // ---- x streams: even loads x[2k+2], odd loads x[2k+3]; F/B buffer pair ----
    f32x4 accA[6], accB[6], accHN[2];
    uint4 xc0 = {}, xc1 = {}, xe0 = {}, xe1 = {};
    float2 xsc = {}, xse = {};
    const unsigned short* xFE = nullptr; const unsigned short* xBE = nullptr;
    const unsigned short* xFO = nullptr; const unsigned short* xBO = nullptr;
    const float* xfpE = nullptr; const float* xfpO = nullptr;

    if constexpr (!IS_L0) {
        const unsigned short* pF = bin + (size_t)t0 * PS + (size_t)(b0 + col) * 32 + qd * 8;
        const unsigned short* pB = pF + DS;
        uint4 a = *(const uint4*)pF, b = *(const uint4*)pB;
        PROJ(accA, a, b, {});                         // acc for step 0
        xc0 = *(const uint4*)(pF + dplane);           // x[1]
        xc1 = *(const uint4*)(pB + dplane);
        xFE = pF + 2 * dplane; xBE = pB + 2 * dplane; // x[2]
        xFO = pF + 3 * dplane; xBO = pB + 3 * dplane; // x[3]
    } else {
        const float* p0 = x0 + ((size_t)(b0 + col) * TT + t0) * 2;
        float2 xs0 = *(const float2*)p0;
        PROJ(accA, {}, {}, xs0);
        xsc = *(const float2*)(p0 + dt * 2);          // x[1]
        xfpE = p0 + dt * 4;                           // x[2]
        xfpO = p0 + dt * 6;                           // x[3]
    }

    unsigned short* optrA = nullptr; unsigned short* optrB = nullptr;
    float* poutA = nullptr; float* poutB = nullptr;
    const ptrdiff_t dpp = (ptrdiff_t)dt * (ptrdiff_t)BB * 2;
    if constexpr (IS_LAST) {
        poutA = pbase + (size_t)d * PT + ((size_t)t0 * BB + b0 + col) * 2;
        poutB = poutA + dpp;
    } else {
        optrA = bout + (size_t)d * DS + (size_t)t0 * PS + (size_t)(b0 + col) * 32 + qd * 8;
        optrB = optrA + dplane;
    }

    // delayed-store state (L0/L1): primed with zero-writes to step-0/1 addresses
    uint4 hwPrevA = {}, hwPrevB = {};
    unsigned short* opPrevA = optrA;
    unsigned short* opPrevB = optrB;

    for (int k = 0; k < 31; ++k) {                    // steps 0..61
        if constexpr (!IS_L0) {
            xe0 = *(const uint4*)xFE; xe1 = *(const uint4*)xBE;
            xFE += 2 * dplane; xBE += 2 * dplane;
        } else { xse = *(const float2*)xfpE; xfpE += dt * 4; }
        REC(accA, accHN);
        PROJ(accB, xc0, xc1, xsc);
        GATES(accA, accHN, optrA, hwPrevA, opPrevA, poutA);
        if constexpr (IS_LAST) poutA += 2 * dpp; else optrA += 2 * dplane;
        if constexpr (!IS_L0) {
            xc0 = *(const uint4*)xFO; xc1 = *(const uint4*)xBO;
            xFO += 2 * dplane; xBO += 2 * dplane;
        } else { xsc = *(const float2*)xfpO; xfpO += dt * 4; }
        REC(accB, accHN);
        PROJ(accA, xe0, xe1, xse);
        GATES(accB, accHN, optrB, hwPrevB, opPrevB, poutB);
        if constexpr (IS_LAST) poutB += 2 * dpp; else optrB += 2 * dplane;
    }
    REC(accA, accHN);                                 // step 62
    PROJ(accB, xc0, xc1, xsc);
    GATES(accA, accHN, optrA, hwPrevA, opPrevA, poutA);
    REC(accB, accHN);                                 // step 63
    GATES(accB, accHN, optrB, hwPrevB, opPrevB, poutB);
    if constexpr (!IS_LAST) {
        *(uint4*)opPrevA = hwPrevA;                   // flush banked values
        *(uint4*)opPrevB = hwPrevB;
    }
}

// out[b][t] = tanh(pf[t][b] + pb[t][b] + bfc), with an LDS 64x64 transpose
__global__ __launch_bounds__(256)
void fc_finish(const float* __restrict__ pf,    // (T,B,2)
               const float* __restrict__ pb,    // (T,B,2)
               const float* __restrict__ bfc,   // (2,)
               float* __restrict__ out)         // (B,T,2)
{
    __shared__ float2 tile[64][65];
    const int tid = threadIdx.x;
    const int bbase = blockIdx.x * 64;
    const float c0 = bfc[0], c1 = bfc[1];
    #pragma unroll
    for (int tp = 0; tp < 16; ++tp) {             // read coalesced over b
        const int t = tp * 4 + (tid >> 6);
        const int bl = tid & 63;
        const size_t idx = ((size_t)t * BB + bbase + bl) * 2;
        float2 vf = *(const float2*)(pf + idx);
        float2 vb = *(const float2*)(pb + idx);
        float2 o;
        o.x = tanh_fast(vf.x + vb.x + c0);
        o.y = tanh_fast(vf.y + vb.y + c1);
        tile[t][bl] = o;
    }
    __syncthreads();
    #pragma unroll
    for (int bp = 0; bp < 16; ++bp) {             // write coalesced over t
        const int bl = bp * 4 + (tid >> 6);
        const int t = tid & 63;
        *(float2*)(out + ((size_t)(bbase + bl) * TT + t) * 2) = tile[t][bl];
    }
}

extern "C" void kernel_launch(void* const* d_in, const int* in_sizes, int n_in,
                              void* d_out, int out_size, void* d_ws, size_t ws_size,
                              hipStream_t stream)
{
    const float* x    = (const float*)d_in[0];
    const float* Wih0 = (const float*)d_in[1];
    const float* Whh0 = (const float*)d_in[2];
    const float* bih0 = (const float*)d_in[3];
    const float* bhh0 = (const float*)d_in[4];
    const float* WihL = (const float*)d_in[5];
    const float* WhhL = (const float*)d_in[6];
    const float* bihL = (const float*)d_in[7];
    const float* bhhL = (const float*)d_in[8];
    const float* Wfc  = (const float*)d_in[9];
    const float* bfc  = (const float*)d_in[10];

    unsigned short* buf0 = (unsigned short*)d_ws;           // (2,T,B,32) f16
    unsigned short* buf1 = buf0 + 2 * DS;                   // (2,T,B,32) f16
    float* pbase = (float*)d_ws;                            // (2,T,B,2) fp32, reuses buf0
    float* out = (float*)d_out;

    gru_mfma<true, false><<<512, 256, 0, stream>>>(
        x, nullptr, Wih0, Whh0, bih0, bhh0, buf0, nullptr, nullptr);
    gru_mfma<false, false><<<512, 256, 0, stream>>>(
        nullptr, buf0, WihL, WhhL, bihL, bhhL, buf1, nullptr, nullptr);
    gru_mfma<false, true><<<512, 256, 0, stream>>>(
        nullptr, buf1, WihL + 2 * 96 * 64, WhhL + 2 * 96 * 32,
        bihL + 2 * 96, bhhL + 2 * 96, nullptr, Wfc, pbase);
    fc_finish<<<BB / 64, 256, 0, stream>>>(
        pbase, pbase + PT, bfc, out);
}